// Round 4
// baseline (339.970 us; speedup 1.0000x reference)
//
#include <hip/hip_runtime.h>
#include <stdint.h>

#define BS 16
#define NP 25200
#define NC 80
#define DIM 85
#define KN 2048
#define CAP 4096
#define BINS 512
#define MAXD 300
#define NBLK 394   // ceil(25200/64)
#define CHUNKS 25  // ceil(25200/1024)

// ---------------------------------------------------------------- score
// Reg-staged: global_load_dwordx4 -> VGPR -> ds_write_b128. Tests the
// global_load_lds drain-rate theory (prev: ~1KB/375cy/CU completion => 82us
// model matched ~100us measured). VMEM->VGPR completes out-of-order and is
// the 6.3 TB/s microbench path. Compute phase unchanged.
__global__ __launch_bounds__(256) void score_kernel(const float* __restrict__ preds,
        float* __restrict__ score, int* __restrict__ clsout) {
    int b = blockIdx.x / NBLK;
    int blk = blockIdx.x % NBLK;
    int i0 = blk * 64;
    int nb = min(64, NP - i0);
    __shared__ float4 s4[64 * DIM / 4];   // 21760 B
    const float4* p4 = (const float4*)(preds + ((size_t)b * NP + i0) * DIM);
    int tot4 = (nb * DIM) >> 2;           // 1360 (full) or 1020 (tail), exact
    // issue all loads first (max MLP), then LDS writes
    float4 tmp[6];
    #pragma unroll
    for (int kx = 0; kx < 6; ++kx) {
        int idx = kx * 256 + threadIdx.x;
        tmp[kx] = (idx < tot4) ? p4[idx] : make_float4(0.f, 0.f, 0.f, 0.f);
    }
    #pragma unroll
    for (int kx = 0; kx < 6; ++kx) {
        int idx = kx * 256 + threadIdx.x;
        if (idx < tot4) s4[idx] = tmp[kx];
    }
    __syncthreads();
    const float* s = (const float*)s4;
    int box = threadIdx.x >> 2, sub = threadIdx.x & 3;
    if (box < nb) {
        const float* bp = s + box * DIM;
        float obj = bp[4];
        float best = -1.0f; int bidx = sub * 20;
        #pragma unroll
        for (int c = 0; c < 20; ++c) {
            float v = bp[5 + sub * 20 + c] * obj;
            if (v > best) { best = v; bidx = sub * 20 + c; }   // strict > keeps first index
        }
        #pragma unroll
        for (int off = 1; off < 4; off <<= 1) {
            float ob = __shfl_xor(best, off);
            int   oi = __shfl_xor(bidx, off);
            if (ob > best || (ob == best && oi < bidx)) { best = ob; bidx = oi; }
        }
        if (sub == 0) {
            bool m = (obj > 0.25f) && (best > 0.25f);
            int gi = b * NP + i0 + box;
            score[gi] = m ? best : -1.0f;
            clsout[gi] = bidx;
        }
    }
}

// ---------------------------------------------------------------- in-wave bitonic
// Generic in-register bitonic sort across one wave (64 lanes x V regs).
// Element e = a*64 + lane (a = register index). DESC=true -> descending.
template<int V, bool DESC, typename T>
__device__ inline void wave_bitonic(T (&v)[V], int lane) {
    const int N = V * 64;
    #pragma unroll
    for (int k = 2; k <= N; k <<= 1) {
        #pragma unroll
        for (int j = N >> 1; j > 0; j >>= 1) {
            if (j >= k) continue;          // strides start at k/2
            if (j >= 64) {
                int dv = j >> 6;
                #pragma unroll
                for (int a = 0; a < V; ++a) {
                    int p = a ^ dv;
                    if (a < p) {
                        int e = a * 64;    // k >= 128 here: lane bits can't hit k
                        bool kml = (((e & k) == 0) == DESC);  // lower keeps max?
                        T lo = v[a], hi = v[p];
                        T mx = lo > hi ? lo : hi;
                        T mn = lo > hi ? hi : lo;
                        v[a] = kml ? mx : mn;
                        v[p] = kml ? mn : mx;
                    }
                }
            } else {
                #pragma unroll
                for (int a = 0; a < V; ++a) {
                    int e = a * 64 + lane;
                    T pv = __shfl_xor(v[a], j);
                    bool isLower = (lane & j) == 0;
                    bool kml = (((e & k) == 0) == DESC);
                    bool takeMax = (kml == isLower);
                    T mx = v[a] > pv ? v[a] : pv;
                    T mn = v[a] > pv ? pv : v[a];
                    v[a] = takeMax ? mx : mn;
                }
            }
        }
    }
}

// ---------------------------------------------------------------- fused tail
// One block per batch. Counting sort replaces bitonic-4096: bin (score bits
// >> 15, 512 bins over (0.25,1]) is a monotone function of score, so
// scatter-by-bin + within-bin descending key sort = exact global descending
// (score, ~idx) order. Within-bin sorts are per-wave in-register bitonic
// (bins <= ~80 elems at this granularity; capacity 256). NMS is per-class
// register/ballot (boxes in lanes, suppression masks in SGPRs): class sep
// >= 7680 > max box span => cross-class IoU exactly 0 (proven, passed R3).
__global__ __launch_bounds__(1024) void fused_tail_kernel(
        const float* __restrict__ score, const float* __restrict__ preds,
        const int* __restrict__ cls, float* __restrict__ out) {
    int b = blockIdx.x;
    int tid = threadIdx.x;
    int lane = tid & 63;
    int wid = tid >> 6;

    __shared__ __attribute__((aligned(16))) char smemA[100800]; // ssc | phase-2 pack
    __shared__ unsigned long long k[CAP];   // 32768 B
    __shared__ int h[BINS];                 // hist -> class hist
    __shared__ int bstartA[BINS];           // bin starts -> class starts
    __shared__ int bcnt[BINS];              // scatter counters -> class counters
    __shared__ int sT;

    float* ssc = (float*)smemA;             // phase 1 only
    // phase-2 overlays (ssc dead after scatter+binsort barrier): 84 KB
    float4* bx4 = (float4*)smemA;                               // 32768
    float4* cbx = (float4*)(smemA + 32768);                     // 32768 class-compacted
    int*    carr = (int*)(smemA + 65536);                       // 8192
    unsigned short* corder = (unsigned short*)(smemA + 73728);  // 4096
    unsigned char*  keepA  = (unsigned char*)(smemA + 77824);   // 2048
    unsigned short* posA   = (unsigned short*)(smemA + 79872);  // 4096

    for (int t = tid; t < BINS; t += 1024) { h[t] = 0; bcnt[t] = 0; }
    __syncthreads();
    // ---- pass A: global -> LDS scores + LDS hist (shift-15 bins)
    const float* sb = score + (size_t)b * NP;
    #pragma unroll
    for (int g = 0; g < 5; ++g) {
        float v[5];
        int idx[5];
        #pragma unroll
        for (int j = 0; j < 5; ++j) {
            idx[j] = (g * 5 + j) * 1024 + tid;
            v[j] = (idx[j] < NP) ? sb[idx[j]] : -1.0f;
        }
        #pragma unroll
        for (int j = 0; j < 5; ++j) {
            if (idx[j] < NP) {
                ssc[idx[j]] = v[j];
                if (v[j] > 0.0f) {
                    int bin = (int)(__float_as_uint(v[j]) >> 15) - 0x7D00;
                    bin = max(0, min(BINS - 1, bin));
                    atomicAdd(&h[bin], 1);
                }
            }
        }
    }
    __syncthreads();
    // ---- threshold + bin starts (wave 0): bstartA[bin] = count in bins > bin
    if (tid < 64) {
        int base = lane * 8;
        int v[8]; int ssum = 0;
        #pragma unroll
        for (int kk = 0; kk < 8; ++kk) { v[kk] = h[base + kk]; ssum += v[kk]; }
        int x = ssum;
        #pragma unroll
        for (int off = 1; off < 64; off <<= 1) {
            int y = __shfl_down(x, off);
            if (lane + off < 64) x += y;
        }
        int run = x - ssum;                    // suffix over bins > base+7
        int cand = -1;
        #pragma unroll
        for (int kk = 7; kk >= 0; --kk) {
            bstartA[base + kk] = run;          // exclusive (bins strictly above)
            run += v[kk];
            if (run >= KN && cand < 0) cand = base + kk;
        }
        #pragma unroll
        for (int off = 1; off < 64; off <<= 1) cand = max(cand, __shfl_xor(cand, off));
        if (lane == 0) sT = max(cand, 0);
    }
    __syncthreads();
    int T = sT;
    int n = min(bstartA[T] + h[T], CAP);       // total candidates (bins >= T)
    int Mb = min(n, KN);
    // ---- scatter candidates into k[] at bin-sorted positions
    for (int c = 0; c < CHUNKS; ++c) {
        int i = c * 1024 + tid;
        if (i < NP) {
            float sc = ssc[i];
            if (sc > 0.0f) {
                int bin = (int)(__float_as_uint(sc) >> 15) - 0x7D00;
                bin = max(0, min(BINS - 1, bin));
                if (bin >= T) {
                    int pos = bstartA[bin] + atomicAdd(&bcnt[bin], 1);
                    if (pos < CAP) {
                        unsigned int ii = (unsigned int)i;
                        k[pos] = ((unsigned long long)__float_as_uint(sc) << 32)
                               | (unsigned int)(~ii);
                    }
                }
            }
        }
    }
    __syncthreads();
    // ---- per-bin descending sort (wave w owns bins with bin%16==w, >= T)
    for (int bin = (T & ~15) + wid; bin < BINS; bin += 16) {
        if (bin < T) continue;
        int cnt = h[bin];
        if (cnt <= 0) continue;
        int bs = bstartA[bin];
        unsigned long long v[4];               // capacity 256/bin (max ~80 expected)
        #pragma unroll
        for (int a = 0; a < 4; ++a) {
            int idx = a * 64 + lane;
            v[a] = (idx < cnt && bs + idx < CAP) ? k[bs + idx] : 0ull;
        }
        wave_bitonic<4, true>(v, lane);
        #pragma unroll
        for (int a = 0; a < 4; ++a) {
            int idx = a * 64 + lane;
            if (idx < cnt && bs + idx < CAP) k[bs + idx] = v[a];
        }
    }
    __syncthreads();
    // ---- build candidates into LDS (ssc dead); zero class arrays
    for (int r = tid; r < KN; r += 1024) {
        keepA[r] = 0;
        if (r < Mb) {
            unsigned long long key = k[r];
            unsigned int i = ~(unsigned int)key;
            const float* p = preds + ((size_t)b * NP + i) * DIM;
            float x = p[0], y = p[1], w = p[2], hh = p[3];
            bx4[r] = make_float4(x - w * 0.5f, y - hh * 0.5f,
                                 x + w * 0.5f, y + hh * 0.5f);
            carr[r] = cls[(size_t)b * NP + i];
        }
    }
    if (tid < 128) { h[tid] = 0; bcnt[tid] = 0; }   // reuse: h=chist, bcnt=ccnt
    __syncthreads();
    // ---- class histogram
    for (int r = tid; r < Mb; r += 1024) atomicAdd(&h[carr[r]], 1);
    __syncthreads();
    // ---- exclusive prefix over 80 class counts (wave 0) -> bstartA = cstart
    if (tid < 64) {
        int a = h[lane];
        int sa = a;
        #pragma unroll
        for (int off = 1; off < 64; off <<= 1) {
            int y = __shfl_up(sa, off);
            if (lane >= off) sa += y;
        }
        bstartA[lane] = sa - a;
        int tot64 = __shfl(sa, 63);
        int b2 = (lane < 16) ? h[64 + lane] : 0;
        int sb2 = b2;
        #pragma unroll
        for (int off = 1; off < 64; off <<= 1) {
            int y = __shfl_up(sb2, off);
            if (lane >= off) sb2 += y;
        }
        if (lane < 16) bstartA[64 + lane] = tot64 + (sb2 - b2);
    }
    __syncthreads();
    // ---- class scatter (arbitrary order) then per-class ascending rank sort
    for (int r = tid; r < Mb; r += 1024) {
        int c = carr[r];
        int pos = bstartA[c] + atomicAdd(&bcnt[c], 1);
        corder[pos] = (unsigned short)r;
    }
    __syncthreads();
    #pragma unroll
    for (int t5 = 0; t5 < 5; ++t5) {
        int c = wid + 16 * t5;
        int nc = h[c];
        int bs = bstartA[c];
        if (nc > 0) {                          // nc <= 128 (multinomial, P(>128)~e^-80)
            unsigned int v[2];
            v[0] = (lane < nc) ? (unsigned int)corder[bs + lane] : 0xFFFFFFFFu;
            v[1] = (lane + 64 < nc) ? (unsigned int)corder[bs + 64 + lane] : 0xFFFFFFFFu;
            wave_bitonic<2, false>(v, lane);   // ascending by rank
            if (lane < nc) corder[bs + lane] = (unsigned short)v[0];
            if (lane + 64 < nc) corder[bs + 64 + lane] = (unsigned short)v[1];
        }
    }
    __syncthreads();
    // ---- class-compacted boxes
    for (int p = tid; p < Mb; p += 1024) cbx[p] = bx4[corder[p]];
    __syncthreads();
    // ---- per-class register/ballot NMS (wave w: classes w, w+16, ...)
    #pragma unroll
    for (int t5 = 0; t5 < 5; ++t5) {
        int c = wid + 16 * t5;
        int nc = h[c];
        int bs = bstartA[c];
        if (nc <= 0) continue;
        float off = (float)c * 7680.0f;
        float4 A0 = make_float4(0.f, 0.f, 0.f, 0.f), A1 = A0;
        if (lane < nc) A0 = cbx[bs + lane];
        if (lane + 64 < nc) A1 = cbx[bs + 64 + lane];
        // offset boxes exactly as reference builds them (bx + cls*7680)
        A0.x += off; A0.y += off; A0.z += off; A0.w += off;
        A1.x += off; A1.y += off; A1.z += off; A1.w += off;
        float ar0 = (A0.z - A0.x) * (A0.w - A0.y);
        float ar1 = (A1.z - A1.x) * (A1.w - A1.y);
        unsigned long long sup0 = 0, sup1 = 0, keep0 = 0, keep1 = 0;
        for (int idx = 0; idx < nc; ++idx) {
            bool hi = idx >= 64;
            int bit = idx & 63;
            unsigned long long s = hi ? sup1 : sup0;   // wave-uniform
            if ((s >> bit) & 1ull) continue;           // uniform branch
            if (hi) keep1 |= 1ull << bit; else keep0 |= 1ull << bit;
            float bx_ = hi ? __shfl(A1.x, bit) : __shfl(A0.x, bit);
            float by_ = hi ? __shfl(A1.y, bit) : __shfl(A0.y, bit);
            float bz_ = hi ? __shfl(A1.z, bit) : __shfl(A0.z, bit);
            float bw_ = hi ? __shfl(A1.w, bit) : __shfl(A0.w, bit);
            float ba_ = hi ? __shfl(ar1, bit) : __shfl(ar0, bit);
            bool s0, s1;
            {
                float lx = fmaxf(bx_, A0.x), ly = fmaxf(by_, A0.y);
                float rx = fminf(bz_, A0.z), ry = fminf(bw_, A0.w);
                float iw = fmaxf(rx - lx, 0.0f), ih = fmaxf(ry - ly, 0.0f);
                float inter = iw * ih;
                float iou = inter / (ba_ + ar0 - inter + 1e-7f);  // a_i + a_j order = ref
                s0 = (lane > idx) && (lane < nc) && (iou > 0.45f);
            }
            {
                float lx = fmaxf(bx_, A1.x), ly = fmaxf(by_, A1.y);
                float rx = fminf(bz_, A1.z), ry = fminf(bw_, A1.w);
                float iw = fmaxf(rx - lx, 0.0f), ih = fmaxf(ry - ly, 0.0f);
                float inter = iw * ih;
                float iou = inter / (ba_ + ar1 - inter + 1e-7f);
                s1 = ((64 + lane) > idx) && ((64 + lane) < nc) && (iou > 0.45f);
            }
            sup0 |= __ballot(s0);
            sup1 |= __ballot(s1);
        }
        if (lane < nc && ((keep0 >> lane) & 1ull)) keepA[corder[bs + lane]] = 1;
        if (lane + 64 < nc && ((keep1 >> lane) & 1ull)) keepA[corder[bs + 64 + lane]] = 1;
    }
    __syncthreads();
    // ---- prefix over keep flags in global rank order (wave 0)
    if (tid < 64) {
        int running = 0;
        for (int ch = 0; ch < 32; ++ch) {
            int r = ch * 64 + lane;
            bool kp = keepA[r] != 0;
            unsigned long long m = __ballot(kp);
            if (kp) posA[r] = (unsigned short)(running + __popcll(m & ((1ull << lane) - 1ull)));
            running += (int)__popcll(m);
        }
    }
    __syncthreads();
    // ---- output (out pre-zeroed; rows beyond kept count stay 0)
    for (int r = tid; r < KN; r += 1024) {
        if (keepA[r] && posA[r] < MAXD) {
            float4 bx = bx4[r];
            float sc = __uint_as_float((unsigned int)(k[r] >> 32));
            int c = carr[r];
            float* o = out + ((size_t)b * MAXD + posA[r]) * 6;
            o[0] = bx.x * 3.0f;      // 1920/640
            o[1] = bx.y * 1.6875f;   // 1080/640
            o[2] = bx.z * 3.0f;
            o[3] = bx.w * 1.6875f;
            o[4] = sc;
            o[5] = (float)c;
        }
    }
}

// ---------------------------------------------------------------- launch
extern "C" void kernel_launch(void* const* d_in, const int* in_sizes, int n_in,
                              void* d_out, int out_size, void* d_ws, size_t ws_size,
                              hipStream_t stream) {
    const float* preds = (const float*)d_in[0];
    float* out = (float*)d_out;
    char* ws = (char*)d_ws;
    size_t off = 0;
    auto alloc = [&](size_t bytes) -> void* {
        void* p = ws + off;
        off += (bytes + 255) & ~(size_t)255;
        return p;
    };
    float* score = (float*)alloc((size_t)BS * NP * 4);
    int* cls    = (int*)alloc((size_t)BS * NP * 4);
    if (ws_size < off) return;

    hipMemsetAsync(d_out, 0, (size_t)out_size * 4, stream);

    score_kernel<<<BS * NBLK, 256, 0, stream>>>(preds, score, cls);
    fused_tail_kernel<<<BS, 1024, 0, stream>>>(score, preds, cls, out);
}

// Round 5
// 292.827 us; speedup vs baseline: 1.1610x; 1.1610x over previous
//
#include <hip/hip_runtime.h>
#include <stdint.h>

#define BS 16
#define NP 25200
#define NC 80
#define DIM 85
#define KN 2048
#define CAP 4096
#define BINS 512
#define MAXD 300
#define NBLK 394   // ceil(25200/64)

// ---------------------------------------------------------------- score
// Unchanged from R4 (reg-staged). Measured equal to global_load_lds variant;
// held constant this round for attribution.
__global__ __launch_bounds__(256) void score_kernel(const float* __restrict__ preds,
        float* __restrict__ score, int* __restrict__ clsout) {
    int b = blockIdx.x / NBLK;
    int blk = blockIdx.x % NBLK;
    int i0 = blk * 64;
    int nb = min(64, NP - i0);
    __shared__ float4 s4[64 * DIM / 4];   // 21760 B
    const float4* p4 = (const float4*)(preds + ((size_t)b * NP + i0) * DIM);
    int tot4 = (nb * DIM) >> 2;           // 1360 (full) or 1020 (tail), exact
    float4 tmp[6];
    #pragma unroll
    for (int kx = 0; kx < 6; ++kx) {
        int idx = kx * 256 + threadIdx.x;
        tmp[kx] = (idx < tot4) ? p4[idx] : make_float4(0.f, 0.f, 0.f, 0.f);
    }
    #pragma unroll
    for (int kx = 0; kx < 6; ++kx) {
        int idx = kx * 256 + threadIdx.x;
        if (idx < tot4) s4[idx] = tmp[kx];
    }
    __syncthreads();
    const float* s = (const float*)s4;
    int box = threadIdx.x >> 2, sub = threadIdx.x & 3;
    if (box < nb) {
        const float* bp = s + box * DIM;
        float obj = bp[4];
        float best = -1.0f; int bidx = sub * 20;
        #pragma unroll
        for (int c = 0; c < 20; ++c) {
            float v = bp[5 + sub * 20 + c] * obj;
            if (v > best) { best = v; bidx = sub * 20 + c; }   // strict > keeps first index
        }
        #pragma unroll
        for (int off = 1; off < 4; off <<= 1) {
            float ob = __shfl_xor(best, off);
            int   oi = __shfl_xor(bidx, off);
            if (ob > best || (ob == best && oi < bidx)) { best = ob; bidx = oi; }
        }
        if (sub == 0) {
            bool m = (obj > 0.25f) && (best > 0.25f);
            int gi = b * NP + i0 + box;
            score[gi] = m ? best : -1.0f;
            clsout[gi] = bidx;
        }
    }
}

// ---------------------------------------------------------------- in-wave bitonic
template<int V, bool DESC, typename T>
__device__ inline void wave_bitonic(T (&v)[V], int lane) {
    const int N = V * 64;
    #pragma unroll
    for (int k = 2; k <= N; k <<= 1) {
        #pragma unroll
        for (int j = N >> 1; j > 0; j >>= 1) {
            if (j >= k) continue;          // strides start at k/2
            if (j >= 64) {
                int dv = j >> 6;
                #pragma unroll
                for (int a = 0; a < V; ++a) {
                    int p = a ^ dv;
                    if (a < p) {
                        int e = a * 64;    // k >= 128 here: lane bits can't hit k
                        bool kml = (((e & k) == 0) == DESC);  // lower keeps max?
                        T lo = v[a], hi = v[p];
                        T mx = lo > hi ? lo : hi;
                        T mn = lo > hi ? hi : lo;
                        v[a] = kml ? mx : mn;
                        v[p] = kml ? mn : mx;
                    }
                }
            } else {
                #pragma unroll
                for (int a = 0; a < V; ++a) {
                    int e = a * 64 + lane;
                    T pv = __shfl_xor(v[a], j);
                    bool isLower = (lane & j) == 0;
                    bool kml = (((e & k) == 0) == DESC);
                    bool takeMax = (kml == isLower);
                    T mx = v[a] > pv ? v[a] : pv;
                    T mn = v[a] > pv ? pv : v[a];
                    v[a] = takeMax ? mx : mn;
                }
            }
        }
    }
}

// ---------------------------------------------------------------- sort (phase kernel)
// One block per batch. hist -> threshold -> scatter -> per-bin sort ->
// build candidates + per-class ordered lists. All phase math verbatim R4
// (bit-exact-passing); ssc LDS staging dropped (scores re-read from L3-hot
// global). Writes gkeys/gboxes/gcarr/gcorder/gcstart/gccnt + zeroed keepG.
__global__ __launch_bounds__(1024) void sort_kernel(
        const float* __restrict__ score, const float* __restrict__ preds,
        const int* __restrict__ cls,
        unsigned long long* __restrict__ gkeys, float4* __restrict__ gboxes,
        int* __restrict__ gcarr, unsigned short* __restrict__ gcorder,
        int* __restrict__ gcstart, int* __restrict__ gccnt,
        unsigned char* __restrict__ keepG) {
    int b = blockIdx.x;
    int tid = threadIdx.x;
    int lane = tid & 63;
    int wid = tid >> 6;

    __shared__ unsigned long long k[CAP];   // 32 KB
    __shared__ int h[BINS];                 // hist -> class hist
    __shared__ int bstartA[BINS];           // bin starts -> class starts
    __shared__ int bcnt[BINS];              // scatter counters -> class counters
    __shared__ int carr[KN];                // 8 KB
    __shared__ unsigned short corder[KN];   // 4 KB
    __shared__ int sT;

    for (int t = tid; t < BINS; t += 1024) { h[t] = 0; bcnt[t] = 0; }
    __syncthreads();
    // ---- pass 1: histogram (shift-15 bins), direct from global
    const float* sb = score + (size_t)b * NP;
    for (int i = tid; i < NP; i += 1024) {
        float v = sb[i];
        if (v > 0.0f) {
            int bin = (int)(__float_as_uint(v) >> 15) - 0x7D00;
            bin = max(0, min(BINS - 1, bin));
            atomicAdd(&h[bin], 1);
        }
    }
    __syncthreads();
    // ---- threshold + bin starts (wave 0), verbatim R4
    if (tid < 64) {
        int base = lane * 8;
        int v[8]; int ssum = 0;
        #pragma unroll
        for (int kk = 0; kk < 8; ++kk) { v[kk] = h[base + kk]; ssum += v[kk]; }
        int x = ssum;
        #pragma unroll
        for (int off = 1; off < 64; off <<= 1) {
            int y = __shfl_down(x, off);
            if (lane + off < 64) x += y;
        }
        int run = x - ssum;                    // suffix over bins > base+7
        int cand = -1;
        #pragma unroll
        for (int kk = 7; kk >= 0; --kk) {
            bstartA[base + kk] = run;          // exclusive (bins strictly above)
            run += v[kk];
            if (run >= KN && cand < 0) cand = base + kk;
        }
        #pragma unroll
        for (int off = 1; off < 64; off <<= 1) cand = max(cand, __shfl_xor(cand, off));
        if (lane == 0) sT = max(cand, 0);
    }
    __syncthreads();
    int T = sT;
    int n = min(bstartA[T] + h[T], CAP);       // total candidates (bins >= T)
    int Mb = min(n, KN);
    // ---- pass 2: scatter qualifying scores into k[] at bin positions
    for (int i = tid; i < NP; i += 1024) {
        float sc = sb[i];
        if (sc > 0.0f) {
            int bin = (int)(__float_as_uint(sc) >> 15) - 0x7D00;
            bin = max(0, min(BINS - 1, bin));
            if (bin >= T) {
                int pos = bstartA[bin] + atomicAdd(&bcnt[bin], 1);
                if (pos < CAP) {
                    unsigned int ii = (unsigned int)i;
                    k[pos] = ((unsigned long long)__float_as_uint(sc) << 32)
                           | (unsigned int)(~ii);
                }
            }
        }
    }
    __syncthreads();
    // ---- per-bin descending sort (wave w owns bins with bin%16==w, >= T)
    for (int bin = (T & ~15) + wid; bin < BINS; bin += 16) {
        if (bin < T) continue;
        int cnt = h[bin];
        if (cnt <= 0) continue;
        int bs = bstartA[bin];
        unsigned long long v[4];               // capacity 256/bin
        #pragma unroll
        for (int a = 0; a < 4; ++a) {
            int idx = a * 64 + lane;
            v[a] = (idx < cnt && bs + idx < CAP) ? k[bs + idx] : 0ull;
        }
        wave_bitonic<4, true>(v, lane);
        #pragma unroll
        for (int a = 0; a < 4; ++a) {
            int idx = a * 64 + lane;
            if (idx < cnt && bs + idx < CAP) k[bs + idx] = v[a];
        }
    }
    __syncthreads();
    // ---- build candidates -> global; zero keepG
    for (int r = tid; r < KN; r += 1024) {
        keepG[b * KN + r] = 0;
        if (r < Mb) {
            unsigned long long key = k[r];
            unsigned int i = ~(unsigned int)key;
            const float* p = preds + ((size_t)b * NP + i) * DIM;
            float x = p[0], y = p[1], w = p[2], hh = p[3];
            float4 bx = make_float4(x - w * 0.5f, y - hh * 0.5f,
                                    x + w * 0.5f, y + hh * 0.5f);
            int c = cls[(size_t)b * NP + i];
            gboxes[b * KN + r] = bx;
            gkeys [b * KN + r] = key;
            gcarr [b * KN + r] = c;
            carr[r] = c;
        }
    }
    if (tid < 128) { h[tid] = 0; bcnt[tid] = 0; }   // reuse: h=chist, bcnt=ccnt
    __syncthreads();
    // ---- class histogram
    for (int r = tid; r < Mb; r += 1024) atomicAdd(&h[carr[r]], 1);
    __syncthreads();
    // ---- exclusive prefix over 80 class counts (wave 0) -> bstartA = cstart
    if (tid < 64) {
        int a = h[lane];
        int sa = a;
        #pragma unroll
        for (int off = 1; off < 64; off <<= 1) {
            int y = __shfl_up(sa, off);
            if (lane >= off) sa += y;
        }
        bstartA[lane] = sa - a;
        int tot64 = __shfl(sa, 63);
        int b2 = (lane < 16) ? h[64 + lane] : 0;
        int sb2 = b2;
        #pragma unroll
        for (int off = 1; off < 64; off <<= 1) {
            int y = __shfl_up(sb2, off);
            if (lane >= off) sb2 += y;
        }
        if (lane < 16) bstartA[64 + lane] = tot64 + (sb2 - b2);
    }
    __syncthreads();
    // ---- class scatter (arbitrary order) then per-class ascending rank sort
    for (int r = tid; r < Mb; r += 1024) {
        int c = carr[r];
        int pos = bstartA[c] + atomicAdd(&bcnt[c], 1);
        corder[pos] = (unsigned short)r;
    }
    __syncthreads();
    #pragma unroll
    for (int t5 = 0; t5 < 5; ++t5) {
        int c = wid + 16 * t5;
        int nc = h[c];
        int bs = bstartA[c];
        if (nc > 0) {                          // nc <= 128 (multinomial tail ~0)
            unsigned int v[2];
            v[0] = (lane < nc) ? (unsigned int)corder[bs + lane] : 0xFFFFFFFFu;
            v[1] = (lane + 64 < nc) ? (unsigned int)corder[bs + 64 + lane] : 0xFFFFFFFFu;
            wave_bitonic<2, false>(v, lane);   // ascending by rank
            if (lane < nc) corder[bs + lane] = (unsigned short)v[0];
            if (lane + 64 < nc) corder[bs + 64 + lane] = (unsigned short)v[1];
        }
    }
    __syncthreads();
    // ---- write class metadata
    for (int t = tid; t < Mb; t += 1024) gcorder[b * KN + t] = corder[t];
    if (tid < NC) { gcstart[b * NC + tid] = bstartA[tid]; gccnt[b * NC + tid] = h[tid]; }
}

// ---------------------------------------------------------------- NMS (1280 blocks)
// One wave per (batch, class). Ballot NMS verbatim R4; boxes gathered via
// corder indirection (same values as R4's cbx compaction).
__global__ __launch_bounds__(64) void nms_kernel(const float4* __restrict__ gboxes,
        const unsigned short* __restrict__ gcorder, const int* __restrict__ gcstart,
        const int* __restrict__ gccnt, unsigned char* __restrict__ keepG) {
    int b = blockIdx.x / NC;
    int c = blockIdx.x % NC;
    int nc = gccnt[b * NC + c];
    if (nc <= 0) return;
    int bs = gcstart[b * NC + c];
    int lane = threadIdx.x;
    int ord0 = (lane < nc) ? (int)gcorder[b * KN + bs + lane] : 0;
    int ord1 = (lane + 64 < nc) ? (int)gcorder[b * KN + bs + 64 + lane] : 0;
    float4 A0 = (lane < nc) ? gboxes[b * KN + ord0] : make_float4(0.f, 0.f, 0.f, 0.f);
    float4 A1 = (lane + 64 < nc) ? gboxes[b * KN + ord1] : make_float4(0.f, 0.f, 0.f, 0.f);
    float off = (float)c * 7680.0f;
    A0.x += off; A0.y += off; A0.z += off; A0.w += off;
    A1.x += off; A1.y += off; A1.z += off; A1.w += off;
    float ar0 = (A0.z - A0.x) * (A0.w - A0.y);
    float ar1 = (A1.z - A1.x) * (A1.w - A1.y);
    unsigned long long sup0 = 0, sup1 = 0, keep0 = 0, keep1 = 0;
    for (int idx = 0; idx < nc; ++idx) {
        bool hi = idx >= 64;
        int bit = idx & 63;
        unsigned long long s = hi ? sup1 : sup0;   // wave-uniform
        if ((s >> bit) & 1ull) continue;           // uniform branch
        if (hi) keep1 |= 1ull << bit; else keep0 |= 1ull << bit;
        float bx_ = hi ? __shfl(A1.x, bit) : __shfl(A0.x, bit);
        float by_ = hi ? __shfl(A1.y, bit) : __shfl(A0.y, bit);
        float bz_ = hi ? __shfl(A1.z, bit) : __shfl(A0.z, bit);
        float bw_ = hi ? __shfl(A1.w, bit) : __shfl(A0.w, bit);
        float ba_ = hi ? __shfl(ar1, bit) : __shfl(ar0, bit);
        bool s0, s1;
        {
            float lx = fmaxf(bx_, A0.x), ly = fmaxf(by_, A0.y);
            float rx = fminf(bz_, A0.z), ry = fminf(bw_, A0.w);
            float iw = fmaxf(rx - lx, 0.0f), ih = fmaxf(ry - ly, 0.0f);
            float inter = iw * ih;
            float iou = inter / (ba_ + ar0 - inter + 1e-7f);  // a_i + a_j order = ref
            s0 = (lane > idx) && (lane < nc) && (iou > 0.45f);
        }
        {
            float lx = fmaxf(bx_, A1.x), ly = fmaxf(by_, A1.y);
            float rx = fminf(bz_, A1.z), ry = fminf(bw_, A1.w);
            float iw = fmaxf(rx - lx, 0.0f), ih = fmaxf(ry - ly, 0.0f);
            float inter = iw * ih;
            float iou = inter / (ba_ + ar1 - inter + 1e-7f);
            s1 = ((64 + lane) > idx) && ((64 + lane) < nc) && (iou > 0.45f);
        }
        sup0 |= __ballot(s0);
        sup1 |= __ballot(s1);
    }
    if (lane < nc && ((keep0 >> lane) & 1ull)) keepG[b * KN + ord0] = 1;
    if (lane + 64 < nc && ((keep1 >> lane) & 1ull)) keepG[b * KN + ord1] = 1;
}

// ---------------------------------------------------------------- output
// One wave per batch: prefix over keep flags in global rank order + write.
__global__ __launch_bounds__(64) void out_kernel(const unsigned char* __restrict__ keepG,
        const unsigned long long* __restrict__ gkeys, const float4* __restrict__ gboxes,
        const int* __restrict__ gcarr, float* __restrict__ out) {
    int b = blockIdx.x;
    int lane = threadIdx.x;
    int running = 0;
    for (int ch = 0; ch < 32; ++ch) {
        int r = ch * 64 + lane;
        bool kp = keepG[b * KN + r] != 0;
        unsigned long long m = __ballot(kp);
        int pos = running + (int)__popcll(m & ((1ull << lane) - 1ull));
        if (kp && pos < MAXD) {
            float4 bx = gboxes[b * KN + r];
            float sc = __uint_as_float((unsigned int)(gkeys[b * KN + r] >> 32));
            float* o = out + ((size_t)b * MAXD + pos) * 6;
            o[0] = bx.x * 3.0f;      // 1920/640
            o[1] = bx.y * 1.6875f;   // 1080/640
            o[2] = bx.z * 3.0f;
            o[3] = bx.w * 1.6875f;
            o[4] = sc;
            o[5] = (float)gcarr[b * KN + r];
        }
        running += (int)__popcll(m);
    }
}

// ---------------------------------------------------------------- launch
extern "C" void kernel_launch(void* const* d_in, const int* in_sizes, int n_in,
                              void* d_out, int out_size, void* d_ws, size_t ws_size,
                              hipStream_t stream) {
    const float* preds = (const float*)d_in[0];
    float* out = (float*)d_out;
    char* ws = (char*)d_ws;
    size_t off = 0;
    auto alloc = [&](size_t bytes) -> void* {
        void* p = ws + off;
        off += (bytes + 255) & ~(size_t)255;
        return p;
    };
    float* score = (float*)alloc((size_t)BS * NP * 4);
    int* cls    = (int*)alloc((size_t)BS * NP * 4);
    unsigned long long* gkeys = (unsigned long long*)alloc((size_t)BS * KN * 8);
    float4* gboxes = (float4*)alloc((size_t)BS * KN * 16);
    int* gcarr  = (int*)alloc((size_t)BS * KN * 4);
    unsigned short* gcorder = (unsigned short*)alloc((size_t)BS * KN * 2);
    int* gcstart = (int*)alloc((size_t)BS * NC * 4);
    int* gccnt   = (int*)alloc((size_t)BS * NC * 4);
    unsigned char* keepG = (unsigned char*)alloc((size_t)BS * KN);
    if (ws_size < off) return;

    hipMemsetAsync(d_out, 0, (size_t)out_size * 4, stream);

    score_kernel<<<BS * NBLK, 256, 0, stream>>>(preds, score, cls);
    sort_kernel<<<BS, 1024, 0, stream>>>(score, preds, cls, gkeys, gboxes,
            gcarr, gcorder, gcstart, gccnt, keepG);
    nms_kernel<<<BS * NC, 64, 0, stream>>>(gboxes, gcorder, gcstart, gccnt, keepG);
    out_kernel<<<BS, 64, 0, stream>>>(keepG, gkeys, gboxes, gcarr, out);
}

// Round 6
// 262.488 us; speedup vs baseline: 1.2952x; 1.1156x over previous
//
#include <hip/hip_runtime.h>
#include <stdint.h>

#define BS 16
#define NP 25200
#define NC 80
#define DIM 85
#define KN 2048
#define CAP 4096
#define BINS 512
#define MAXD 300
#define SBLK 99    // score blocks per batch (256 boxes each; 99*256=25344)
#define QCAP 128

// ---------------------------------------------------------------- score + hist
// 1 thread = 1 box. obj-gate first: 75% of rows never read their 80 class
// floats (~60MB touched vs 137MB) and there is no LDS staging / block barrier
// on the load path. Per-block 512-bin histogram partial -> global (no global
// atomics). argmax semantics identical to R5 (serial strict > == first-max).
__global__ __launch_bounds__(256) void score_hist_kernel(const float* __restrict__ preds,
        float* __restrict__ score, int* __restrict__ clsout, int* __restrict__ hpart) {
    int b = blockIdx.x / SBLK;
    int chunk = blockIdx.x % SBLK;
    int tid = threadIdx.x;
    __shared__ int h[BINS];
    h[tid] = 0; h[tid + 256] = 0;
    __syncthreads();
    int n = chunk * 256 + tid;
    if (n < NP) {
        const float* bp = preds + ((size_t)b * NP + n) * DIM;
        float obj = bp[4];
        float sc = -1.0f; int bidx = 0;
        if (obj > 0.25f) {
            float best = -1.0f;
            #pragma unroll
            for (int kk = 0; kk < 10; ++kk) {
                float v[8];
                #pragma unroll
                for (int j = 0; j < 8; ++j) v[j] = bp[5 + kk * 8 + j];
                #pragma unroll
                for (int j = 0; j < 8; ++j) {
                    float s = v[j] * obj;                  // same expr/order as R5
                    if (s > best) { best = s; bidx = kk * 8 + j; }  // strict >
                }
            }
            if (best > 0.25f) sc = best;
        }
        int gi = b * NP + n;
        score[gi] = sc;
        clsout[gi] = bidx;
        if (sc > 0.0f) {
            int bin = (int)(__float_as_uint(sc) >> 15) - 0x7D00;
            bin = max(0, min(BINS - 1, bin));
            atomicAdd(&h[bin], 1);
        }
    }
    __syncthreads();
    int* hp = hpart + ((size_t)(b * SBLK + chunk)) * BINS;
    hp[tid] = h[tid];
    hp[tid + 256] = h[tid + 256];
}

// ---------------------------------------------------------------- in-wave bitonic
template<int V, bool DESC, typename T>
__device__ inline void wave_bitonic(T (&v)[V], int lane) {
    const int N = V * 64;
    #pragma unroll
    for (int k = 2; k <= N; k <<= 1) {
        #pragma unroll
        for (int j = N >> 1; j > 0; j >>= 1) {
            if (j >= k) continue;          // strides start at k/2
            if (j >= 64) {
                int dv = j >> 6;
                #pragma unroll
                for (int a = 0; a < V; ++a) {
                    int p = a ^ dv;
                    if (a < p) {
                        int e = a * 64;    // k >= 128 here: lane bits can't hit k
                        bool kml = (((e & k) == 0) == DESC);
                        T lo = v[a], hi = v[p];
                        T mx = lo > hi ? lo : hi;
                        T mn = lo > hi ? hi : lo;
                        v[a] = kml ? mx : mn;
                        v[p] = kml ? mn : mx;
                    }
                }
            } else {
                #pragma unroll
                for (int a = 0; a < V; ++a) {
                    int e = a * 64 + lane;
                    T pv = __shfl_xor(v[a], j);
                    bool isLower = (lane & j) == 0;
                    bool kml = (((e & k) == 0) == DESC);
                    bool takeMax = (kml == isLower);
                    T mx = v[a] > pv ? v[a] : pv;
                    T mn = v[a] > pv ? pv : v[a];
                    v[a] = takeMax ? mx : mn;
                }
            }
        }
    }
}

// ---------------------------------------------------------------- sort16
// One block per batch, only the phases that are inherently per-batch serial:
// reduce hist partials -> threshold/bin-starts -> scatter keys to global ->
// zero keep/class arrays -> write metadata. Bin sorting & candidate build
// moved to the wide binsort_build kernel.
__global__ __launch_bounds__(1024) void sort16_kernel(const float* __restrict__ score,
        const int* __restrict__ hpart,
        unsigned long long* __restrict__ gkeys, int* __restrict__ gmeta,
        int* __restrict__ gbstart, int* __restrict__ gcnt,
        unsigned char* __restrict__ carrU8, unsigned char* __restrict__ keepG) {
    int b = blockIdx.x;
    int tid = threadIdx.x;
    int lane = tid & 63;
    __shared__ int h[BINS];
    __shared__ int bstartA[BINS];
    __shared__ int bcnt[BINS];
    __shared__ int sT;
    // ---- reduce SBLK partial hists
    if (tid < BINS) {
        int s = 0;
        const int* hp = hpart + ((size_t)b * SBLK) * BINS + tid;
        for (int c = 0; c < SBLK; ++c) s += hp[c * BINS];
        h[tid] = s;
        bcnt[tid] = 0;
    }
    __syncthreads();
    // ---- threshold + bin starts (wave 0), verbatim R5
    if (tid < 64) {
        int base = lane * 8;
        int v[8]; int ssum = 0;
        #pragma unroll
        for (int kk = 0; kk < 8; ++kk) { v[kk] = h[base + kk]; ssum += v[kk]; }
        int x = ssum;
        #pragma unroll
        for (int off = 1; off < 64; off <<= 1) {
            int y = __shfl_down(x, off);
            if (lane + off < 64) x += y;
        }
        int run = x - ssum;                    // suffix over bins > base+7
        int cand = -1;
        #pragma unroll
        for (int kk = 7; kk >= 0; --kk) {
            bstartA[base + kk] = run;          // exclusive (bins strictly above)
            run += v[kk];
            if (run >= KN && cand < 0) cand = base + kk;
        }
        #pragma unroll
        for (int off = 1; off < 64; off <<= 1) cand = max(cand, __shfl_xor(cand, off));
        if (lane == 0) sT = max(cand, 0);
    }
    __syncthreads();
    int T = sT;
    int n = min(bstartA[T] + h[T], CAP);
    int Mb = min(n, KN);
    // ---- scatter qualifying scores into gkeys at bin positions
    const float* sb = score + (size_t)b * NP;
    for (int i = tid; i < NP; i += 1024) {
        float sc = sb[i];
        if (sc > 0.0f) {
            int bin = (int)(__float_as_uint(sc) >> 15) - 0x7D00;
            bin = max(0, min(BINS - 1, bin));
            if (bin >= T) {
                int pos = bstartA[bin] + atomicAdd(&bcnt[bin], 1);
                if (pos < CAP) {
                    unsigned int ii = (unsigned int)i;
                    gkeys[(size_t)b * CAP + pos] =
                        ((unsigned long long)__float_as_uint(sc) << 32)
                        | (unsigned int)(~ii);
                }
            }
        }
    }
    // ---- zero keep flags, mark class array invalid (slots >= Mb stay 0xFF)
    for (int r = tid; r < KN; r += 1024) { keepG[b * KN + r] = 0; carrU8[b * KN + r] = 0xFF; }
    // ---- metadata
    if (tid < BINS) { gbstart[b * BINS + tid] = bstartA[tid]; gcnt[b * BINS + tid] = h[tid]; }
    if (tid == 0) { gmeta[2 * b] = T; gmeta[2 * b + 1] = Mb; }
}

// ---------------------------------------------------------------- binsort + build (wide)
// 32 blocks x 4 waves per batch (128 waves/batch). Each wave sorts its bins
// (<=256 keys, in-register bitonic, verbatim R4/R5 math) and immediately
// builds the candidates for the slots it sorted.
__global__ __launch_bounds__(256) void binsort_build_kernel(const float* __restrict__ preds,
        const int* __restrict__ cls, unsigned long long* __restrict__ gkeys,
        const int* __restrict__ gmeta, const int* __restrict__ gbstart,
        const int* __restrict__ gcnt,
        float4* __restrict__ gboxes, unsigned char* __restrict__ carrU8) {
    int b = blockIdx.x >> 5;
    int g = blockIdx.x & 31;
    int lane = threadIdx.x & 63;
    int wv = threadIdx.x >> 6;
    int T = gmeta[2 * b];
    int Mb = gmeta[2 * b + 1];
    int wslot = g * 4 + wv;                    // 0..127
    for (int bin = T + wslot; bin < BINS; bin += 128) {
        int cnt = gcnt[b * BINS + bin];
        if (cnt <= 0) continue;
        int bs = gbstart[b * BINS + bin];
        if (bs >= Mb) continue;                // entirely beyond the top-KN cut
        unsigned long long v[4];
        #pragma unroll
        for (int a = 0; a < 4; ++a) {
            int idx = a * 64 + lane;
            v[a] = (idx < cnt && bs + idx < CAP) ? gkeys[(size_t)b * CAP + bs + idx] : 0ull;
        }
        wave_bitonic<4, true>(v, lane);
        #pragma unroll
        for (int a = 0; a < 4; ++a) {
            int idx = a * 64 + lane;
            if (idx < cnt && bs + idx < CAP) gkeys[(size_t)b * CAP + bs + idx] = v[a];
        }
        #pragma unroll
        for (int a = 0; a < 4; ++a) {
            int idx = a * 64 + lane;
            int r = bs + idx;
            if (idx < cnt && r < Mb) {
                unsigned long long key = v[a];
                unsigned int i = ~(unsigned int)key;
                const float* p = preds + ((size_t)b * NP + i) * DIM;
                float x = p[0], y = p[1], w = p[2], hh = p[3];
                gboxes[b * KN + r] = make_float4(x - w * 0.5f, y - hh * 0.5f,
                                                x + w * 0.5f, y + hh * 0.5f);
                carrU8[b * KN + r] = (unsigned char)cls[(size_t)b * NP + i];
            }
        }
    }
}

// ---------------------------------------------------------------- NMS (1280 blocks)
// One wave per (batch, class). Builds the rank-ordered class queue by
// streaming the class-id array (ballot compaction — replaces the per-class
// hist/prefix/scatter/sort phases entirely), then the R4/R5 ballot NMS
// verbatim. Cross-class IoU is exactly 0 (class offset 7680 > max span).
__global__ __launch_bounds__(64) void nms_kernel(const float4* __restrict__ gboxes,
        const unsigned char* __restrict__ carrU8, const int* __restrict__ gmeta,
        unsigned char* __restrict__ keepG) {
    int b = blockIdx.x / NC;
    int c = blockIdx.x % NC;
    int lane = threadIdx.x;
    int Mb = gmeta[2 * b + 1];
    __shared__ unsigned short q[QCAP];
    int base = 0;
    for (int r0 = 0; r0 < Mb; r0 += 64) {
        int r = r0 + lane;
        bool mine = (r < Mb) && (carrU8[b * KN + r] == (unsigned char)c);
        unsigned long long m = __ballot(mine);
        int pos = base + (int)__popcll(m & ((1ull << lane) - 1ull));
        if (mine && pos < QCAP) q[pos] = (unsigned short)r;
        base += (int)__popcll(m);
    }
    __syncthreads();
    int nc = min(base, QCAP);
    if (nc <= 0) return;
    int ord0 = (lane < nc) ? (int)q[lane] : 0;
    int ord1 = (lane + 64 < nc) ? (int)q[64 + lane] : 0;
    float4 A0 = (lane < nc) ? gboxes[b * KN + ord0] : make_float4(0.f, 0.f, 0.f, 0.f);
    float4 A1 = (lane + 64 < nc) ? gboxes[b * KN + ord1] : make_float4(0.f, 0.f, 0.f, 0.f);
    float off = (float)c * 7680.0f;
    A0.x += off; A0.y += off; A0.z += off; A0.w += off;
    A1.x += off; A1.y += off; A1.z += off; A1.w += off;
    float ar0 = (A0.z - A0.x) * (A0.w - A0.y);
    float ar1 = (A1.z - A1.x) * (A1.w - A1.y);
    unsigned long long sup0 = 0, sup1 = 0, keep0 = 0, keep1 = 0;
    for (int idx = 0; idx < nc; ++idx) {
        bool hi = idx >= 64;
        int bit = idx & 63;
        unsigned long long s = hi ? sup1 : sup0;   // wave-uniform
        if ((s >> bit) & 1ull) continue;           // uniform branch
        if (hi) keep1 |= 1ull << bit; else keep0 |= 1ull << bit;
        float bx_ = hi ? __shfl(A1.x, bit) : __shfl(A0.x, bit);
        float by_ = hi ? __shfl(A1.y, bit) : __shfl(A0.y, bit);
        float bz_ = hi ? __shfl(A1.z, bit) : __shfl(A0.z, bit);
        float bw_ = hi ? __shfl(A1.w, bit) : __shfl(A0.w, bit);
        float ba_ = hi ? __shfl(ar1, bit) : __shfl(ar0, bit);
        bool s0, s1;
        {
            float lx = fmaxf(bx_, A0.x), ly = fmaxf(by_, A0.y);
            float rx = fminf(bz_, A0.z), ry = fminf(bw_, A0.w);
            float iw = fmaxf(rx - lx, 0.0f), ih = fmaxf(ry - ly, 0.0f);
            float inter = iw * ih;
            float iou = inter / (ba_ + ar0 - inter + 1e-7f);  // a_i + a_j order = ref
            s0 = (lane > idx) && (lane < nc) && (iou > 0.45f);
        }
        {
            float lx = fmaxf(bx_, A1.x), ly = fmaxf(by_, A1.y);
            float rx = fminf(bz_, A1.z), ry = fminf(bw_, A1.w);
            float iw = fmaxf(rx - lx, 0.0f), ih = fmaxf(ry - ly, 0.0f);
            float inter = iw * ih;
            float iou = inter / (ba_ + ar1 - inter + 1e-7f);
            s1 = ((64 + lane) > idx) && ((64 + lane) < nc) && (iou > 0.45f);
        }
        sup0 |= __ballot(s0);
        sup1 |= __ballot(s1);
    }
    if (lane < nc && ((keep0 >> lane) & 1ull)) keepG[b * KN + ord0] = 1;
    if (lane + 64 < nc && ((keep1 >> lane) & 1ull)) keepG[b * KN + ord1] = 1;
}

// ---------------------------------------------------------------- output
__global__ __launch_bounds__(64) void out_kernel(const unsigned char* __restrict__ keepG,
        const unsigned long long* __restrict__ gkeys, const float4* __restrict__ gboxes,
        const unsigned char* __restrict__ carrU8, float* __restrict__ out) {
    int b = blockIdx.x;
    int lane = threadIdx.x;
    int running = 0;
    for (int ch = 0; ch < 32; ++ch) {
        int r = ch * 64 + lane;
        bool kp = keepG[b * KN + r] != 0;
        unsigned long long m = __ballot(kp);
        int pos = running + (int)__popcll(m & ((1ull << lane) - 1ull));
        if (kp && pos < MAXD) {
            float4 bx = gboxes[b * KN + r];
            float sc = __uint_as_float((unsigned int)(gkeys[(size_t)b * CAP + r] >> 32));
            float* o = out + ((size_t)b * MAXD + pos) * 6;
            o[0] = bx.x * 3.0f;      // 1920/640
            o[1] = bx.y * 1.6875f;   // 1080/640
            o[2] = bx.z * 3.0f;
            o[3] = bx.w * 1.6875f;
            o[4] = sc;
            o[5] = (float)carrU8[b * KN + r];
        }
        running += (int)__popcll(m);
    }
}

// ---------------------------------------------------------------- launch
extern "C" void kernel_launch(void* const* d_in, const int* in_sizes, int n_in,
                              void* d_out, int out_size, void* d_ws, size_t ws_size,
                              hipStream_t stream) {
    const float* preds = (const float*)d_in[0];
    float* out = (float*)d_out;
    char* ws = (char*)d_ws;
    size_t off = 0;
    auto alloc = [&](size_t bytes) -> void* {
        void* p = ws + off;
        off += (bytes + 255) & ~(size_t)255;
        return p;
    };
    float* score = (float*)alloc((size_t)BS * NP * 4);
    int* cls    = (int*)alloc((size_t)BS * NP * 4);
    int* hpart  = (int*)alloc((size_t)BS * SBLK * BINS * 4);
    unsigned long long* gkeys = (unsigned long long*)alloc((size_t)BS * CAP * 8);
    float4* gboxes = (float4*)alloc((size_t)BS * KN * 16);
    unsigned char* carrU8 = (unsigned char*)alloc((size_t)BS * KN);
    unsigned char* keepG  = (unsigned char*)alloc((size_t)BS * KN);
    int* gmeta   = (int*)alloc(BS * 2 * 4);
    int* gbstart = (int*)alloc((size_t)BS * BINS * 4);
    int* gcnt    = (int*)alloc((size_t)BS * BINS * 4);
    if (ws_size < off) return;

    hipMemsetAsync(d_out, 0, (size_t)out_size * 4, stream);

    score_hist_kernel<<<BS * SBLK, 256, 0, stream>>>(preds, score, cls, hpart);
    sort16_kernel<<<BS, 1024, 0, stream>>>(score, hpart, gkeys, gmeta, gbstart, gcnt,
                                           carrU8, keepG);
    binsort_build_kernel<<<BS * 32, 256, 0, stream>>>(preds, cls, gkeys, gmeta,
                                                      gbstart, gcnt, gboxes, carrU8);
    nms_kernel<<<BS * NC, 64, 0, stream>>>(gboxes, carrU8, gmeta, keepG);
    out_kernel<<<BS, 64, 0, stream>>>(keepG, gkeys, gboxes, carrU8, out);
}

// Round 7
// 256.903 us; speedup vs baseline: 1.3233x; 1.0217x over previous
//
#include <hip/hip_runtime.h>
#include <stdint.h>

#define BS 16
#define NP 25200
#define NC 80
#define DIM 85
#define KN 2048
#define CAP 4096
#define BINS 512
#define MAXD 300
#define SCB 128    // score blocks per batch
#define QCAP 128

// ---------------------------------------------------------------- score + hist
// Software-pipelined (T14 issue-early/write-late): 128 blocks/batch, each owns
// 3-4 contiguous 64-row groups. Double-buffered LDS; next group's loads are
// issued to VGPRs BEFORE computing the current group, so the CU always has
// ~3 blocks x 24KB in flight (fixes the issue-duty-cycle collapse that held
// all previous variants at ~6 GB/s/CU). Compute phase verbatim R0-R5
// (4 thr/box quad argmax — bit-exact across rounds). Per-block hist partial.
__global__ __launch_bounds__(256) void score_hist_kernel(const float* __restrict__ preds,
        float* __restrict__ score, int* __restrict__ clsout, int* __restrict__ hpart) {
    int b = blockIdx.x >> 7;
    int blk = blockIdx.x & 127;
    int tid = threadIdx.x;
    __shared__ float4 sbuf[2][1360];   // 43520 B
    __shared__ int h[BINS];
    h[tid] = 0; h[tid + 256] = 0;
    int g0  = (blk < 10) ? blk * 4 : blk * 3 + 10;   // 394 groups: 10x4 + 118x3
    int cnt = (blk < 10) ? 4 : 3;
    // prologue: stage group g0 into buf 0
    {
        const float4* p4 = (const float4*)(preds + ((size_t)b * NP + (size_t)g0 * 64) * DIM);
        int nb = min(64, NP - g0 * 64);
        int tot4 = (nb * DIM) >> 2;
        #pragma unroll
        for (int kx = 0; kx < 6; ++kx) {
            int idx = kx * 256 + tid;
            if (idx < tot4) sbuf[0][idx] = p4[idx];
        }
    }
    __syncthreads();
    float4 tmp[6];
    for (int i = 0; i < cnt; ++i) {
        // ---- issue next group's loads (no wait — latency hides under compute)
        int tot4n = 0;
        if (i + 1 < cnt) {
            int g1 = g0 + i + 1;
            int nb1 = min(64, NP - g1 * 64);
            tot4n = (nb1 * DIM) >> 2;
            const float4* p4 = (const float4*)(preds + ((size_t)b * NP + (size_t)g1 * 64) * DIM);
            #pragma unroll
            for (int kx = 0; kx < 6; ++kx) {
                int idx = kx * 256 + tid;
                tmp[kx] = (idx < tot4n) ? p4[idx] : make_float4(0.f, 0.f, 0.f, 0.f);
            }
        }
        // ---- compute current group from sbuf[i&1]
        int gg = g0 + i;
        int nb = min(64, NP - gg * 64);
        const float* s = (const float*)sbuf[i & 1];
        int box = tid >> 2, sub = tid & 3;
        if (box < nb) {
            const float* bp = s + box * DIM;
            float obj = bp[4];
            float best = -1.0f; int bidx = sub * 20;
            #pragma unroll
            for (int c = 0; c < 20; ++c) {
                float v = bp[5 + sub * 20 + c] * obj;
                if (v > best) { best = v; bidx = sub * 20 + c; }   // strict > keeps first
            }
            #pragma unroll
            for (int off = 1; off < 4; off <<= 1) {
                float ob = __shfl_xor(best, off);
                int   oi = __shfl_xor(bidx, off);
                if (ob > best || (ob == best && oi < bidx)) { best = ob; bidx = oi; }
            }
            if (sub == 0) {
                bool m = (obj > 0.25f) && (best > 0.25f);
                float sc = m ? best : -1.0f;
                int gidx = b * NP + gg * 64 + box;
                score[gidx] = sc;
                clsout[gidx] = bidx;
                if (sc > 0.0f) {
                    int bin = (int)(__float_as_uint(sc) >> 15) - 0x7D00;
                    bin = max(0, min(BINS - 1, bin));
                    atomicAdd(&h[bin], 1);
                }
            }
        }
        __syncthreads();           // all done reading sbuf[i&1]
        if (i + 1 < cnt) {
            #pragma unroll
            for (int kx = 0; kx < 6; ++kx) {
                int idx = kx * 256 + tid;
                if (idx < tot4n) sbuf[(i + 1) & 1][idx] = tmp[kx];
            }
            __syncthreads();       // buf ready for next compute
        }
    }
    int* hp = hpart + ((size_t)(b * SCB + blk)) * BINS;
    hp[tid] = h[tid];
    hp[tid + 256] = h[tid + 256];
}

// ---------------------------------------------------------------- threshold + prefix
// 16 blocks x 512. Reduce per-block hist partials -> total hist -> threshold T
// + bin starts (verbatim scan) -> rewrite hpart in place to per-block per-bin
// scatter bases (bstart + exclusive prefix along the 128 source blocks).
// Also zeroes keep/class arrays and writes metadata.
__global__ __launch_bounds__(512) void thresh_kernel(int* __restrict__ hpart,
        int* __restrict__ gmeta, int* __restrict__ gbstart, int* __restrict__ gcnt,
        unsigned char* __restrict__ carrU8, unsigned char* __restrict__ keepG) {
    int b = blockIdx.x;
    int tid = threadIdx.x;     // == bin
    int lane = tid & 63;
    __shared__ int h[BINS];
    __shared__ int bstartA[BINS];
    __shared__ int sT;
    int* hp = hpart + (size_t)b * SCB * BINS;
    int s = 0;
    for (int c = 0; c < SCB; ++c) s += hp[c * BINS + tid];
    h[tid] = s;
    __syncthreads();
    if (tid < 64) {
        int base = lane * 8;
        int v[8]; int ssum = 0;
        #pragma unroll
        for (int kk = 0; kk < 8; ++kk) { v[kk] = h[base + kk]; ssum += v[kk]; }
        int x = ssum;
        #pragma unroll
        for (int off = 1; off < 64; off <<= 1) {
            int y = __shfl_down(x, off);
            if (lane + off < 64) x += y;
        }
        int run = x - ssum;                    // suffix over bins > base+7
        int cand = -1;
        #pragma unroll
        for (int kk = 7; kk >= 0; --kk) {
            bstartA[base + kk] = run;          // exclusive (bins strictly above)
            run += v[kk];
            if (run >= KN && cand < 0) cand = base + kk;
        }
        #pragma unroll
        for (int off = 1; off < 64; off <<= 1) cand = max(cand, __shfl_xor(cand, off));
        if (lane == 0) sT = max(cand, 0);
    }
    __syncthreads();
    int T = sT;
    // in-place: hpart[blk][bin] <- bstart[bin] + sum_{blk'<blk} hpart[blk'][bin]
    int run = bstartA[tid];
    for (int c = 0; c < SCB; ++c) {
        int t = hp[c * BINS + tid];
        hp[c * BINS + tid] = run;
        run += t;
    }
    gbstart[b * BINS + tid] = bstartA[tid];
    gcnt[b * BINS + tid] = h[tid];
    if (tid == 0) {
        int n = min(bstartA[T] + h[T], CAP);
        gmeta[2 * b] = T;
        gmeta[2 * b + 1] = min(n, KN);
    }
    for (int r = tid; r < KN; r += 512) { keepG[b * KN + r] = 0; carrU8[b * KN + r] = 0xFF; }
}

// ---------------------------------------------------------------- scatter (wide)
// Same block partition as score_hist. Each block loads its 512-int base table
// and scatters its own rows' qualifying keys with LDS-local counters only.
// Intra-bin order is nondeterministic but binsort re-sorts by full (score,~idx)
// key, so the final order is exact.
__global__ __launch_bounds__(256) void scatter_kernel(const float* __restrict__ score,
        const int* __restrict__ hpart, const int* __restrict__ gmeta,
        unsigned long long* __restrict__ gkeys) {
    int b = blockIdx.x >> 7;
    int blk = blockIdx.x & 127;
    int tid = threadIdx.x;
    __shared__ int basep[BINS];
    __shared__ int cntL[BINS];
    const int* hp = hpart + (size_t)(b * SCB + blk) * BINS;
    basep[tid] = hp[tid]; basep[tid + 256] = hp[tid + 256];
    cntL[tid] = 0; cntL[tid + 256] = 0;
    __syncthreads();
    int T = gmeta[2 * b];
    int g0  = (blk < 10) ? blk * 4 : blk * 3 + 10;
    int cntg = (blk < 10) ? 4 : 3;
    int r0 = g0 * 64;
    int nrows = min(cntg * 64, NP - r0);
    for (int r = tid; r < nrows; r += 256) {
        int i = r0 + r;
        float sc = score[b * NP + i];
        if (sc > 0.0f) {
            int bin = (int)(__float_as_uint(sc) >> 15) - 0x7D00;
            bin = max(0, min(BINS - 1, bin));
            if (bin >= T) {
                int pos = basep[bin] + atomicAdd(&cntL[bin], 1);
                if (pos < CAP) {
                    unsigned int ii = (unsigned int)i;
                    gkeys[(size_t)b * CAP + pos] =
                        ((unsigned long long)__float_as_uint(sc) << 32)
                        | (unsigned int)(~ii);
                }
            }
        }
    }
}

// ---------------------------------------------------------------- in-wave bitonic
template<int V, bool DESC, typename T>
__device__ inline void wave_bitonic(T (&v)[V], int lane) {
    const int N = V * 64;
    #pragma unroll
    for (int k = 2; k <= N; k <<= 1) {
        #pragma unroll
        for (int j = N >> 1; j > 0; j >>= 1) {
            if (j >= k) continue;          // strides start at k/2
            if (j >= 64) {
                int dv = j >> 6;
                #pragma unroll
                for (int a = 0; a < V; ++a) {
                    int p = a ^ dv;
                    if (a < p) {
                        int e = a * 64;    // k >= 128 here: lane bits can't hit k
                        bool kml = (((e & k) == 0) == DESC);
                        T lo = v[a], hi = v[p];
                        T mx = lo > hi ? lo : hi;
                        T mn = lo > hi ? hi : lo;
                        v[a] = kml ? mx : mn;
                        v[p] = kml ? mn : mx;
                    }
                }
            } else {
                #pragma unroll
                for (int a = 0; a < V; ++a) {
                    int e = a * 64 + lane;
                    T pv = __shfl_xor(v[a], j);
                    bool isLower = (lane & j) == 0;
                    bool kml = (((e & k) == 0) == DESC);
                    bool takeMax = (kml == isLower);
                    T mx = v[a] > pv ? v[a] : pv;
                    T mn = v[a] > pv ? pv : v[a];
                    v[a] = takeMax ? mx : mn;
                }
            }
        }
    }
}

// ---------------------------------------------------------------- binsort + build (wide)
// 32 blocks x 4 waves per batch. Verbatim R6 (passed bit-exact).
__global__ __launch_bounds__(256) void binsort_build_kernel(const float* __restrict__ preds,
        const int* __restrict__ cls, unsigned long long* __restrict__ gkeys,
        const int* __restrict__ gmeta, const int* __restrict__ gbstart,
        const int* __restrict__ gcnt,
        float4* __restrict__ gboxes, unsigned char* __restrict__ carrU8) {
    int b = blockIdx.x >> 5;
    int g = blockIdx.x & 31;
    int lane = threadIdx.x & 63;
    int wv = threadIdx.x >> 6;
    int T = gmeta[2 * b];
    int Mb = gmeta[2 * b + 1];
    int wslot = g * 4 + wv;                    // 0..127
    for (int bin = T + wslot; bin < BINS; bin += 128) {
        int cnt = gcnt[b * BINS + bin];
        if (cnt <= 0) continue;
        int bs = gbstart[b * BINS + bin];
        if (bs >= Mb) continue;                // entirely beyond the top-KN cut
        unsigned long long v[4];
        #pragma unroll
        for (int a = 0; a < 4; ++a) {
            int idx = a * 64 + lane;
            v[a] = (idx < cnt && bs + idx < CAP) ? gkeys[(size_t)b * CAP + bs + idx] : 0ull;
        }
        wave_bitonic<4, true>(v, lane);
        #pragma unroll
        for (int a = 0; a < 4; ++a) {
            int idx = a * 64 + lane;
            if (idx < cnt && bs + idx < CAP) gkeys[(size_t)b * CAP + bs + idx] = v[a];
        }
        #pragma unroll
        for (int a = 0; a < 4; ++a) {
            int idx = a * 64 + lane;
            int r = bs + idx;
            if (idx < cnt && r < Mb) {
                unsigned long long key = v[a];
                unsigned int i = ~(unsigned int)key;
                const float* p = preds + ((size_t)b * NP + i) * DIM;
                float x = p[0], y = p[1], w = p[2], hh = p[3];
                gboxes[b * KN + r] = make_float4(x - w * 0.5f, y - hh * 0.5f,
                                                x + w * 0.5f, y + hh * 0.5f);
                carrU8[b * KN + r] = (unsigned char)cls[(size_t)b * NP + i];
            }
        }
    }
}

// ---------------------------------------------------------------- NMS (1280 blocks)
// One wave per (batch, class). Verbatim R6 (passed bit-exact).
__global__ __launch_bounds__(64) void nms_kernel(const float4* __restrict__ gboxes,
        const unsigned char* __restrict__ carrU8, const int* __restrict__ gmeta,
        unsigned char* __restrict__ keepG) {
    int b = blockIdx.x / NC;
    int c = blockIdx.x % NC;
    int lane = threadIdx.x;
    int Mb = gmeta[2 * b + 1];
    __shared__ unsigned short q[QCAP];
    int base = 0;
    for (int r0 = 0; r0 < Mb; r0 += 64) {
        int r = r0 + lane;
        bool mine = (r < Mb) && (carrU8[b * KN + r] == (unsigned char)c);
        unsigned long long m = __ballot(mine);
        int pos = base + (int)__popcll(m & ((1ull << lane) - 1ull));
        if (mine && pos < QCAP) q[pos] = (unsigned short)r;
        base += (int)__popcll(m);
    }
    __syncthreads();
    int nc = min(base, QCAP);
    if (nc <= 0) return;
    int ord0 = (lane < nc) ? (int)q[lane] : 0;
    int ord1 = (lane + 64 < nc) ? (int)q[64 + lane] : 0;
    float4 A0 = (lane < nc) ? gboxes[b * KN + ord0] : make_float4(0.f, 0.f, 0.f, 0.f);
    float4 A1 = (lane + 64 < nc) ? gboxes[b * KN + ord1] : make_float4(0.f, 0.f, 0.f, 0.f);
    float off = (float)c * 7680.0f;
    A0.x += off; A0.y += off; A0.z += off; A0.w += off;
    A1.x += off; A1.y += off; A1.z += off; A1.w += off;
    float ar0 = (A0.z - A0.x) * (A0.w - A0.y);
    float ar1 = (A1.z - A1.x) * (A1.w - A1.y);
    unsigned long long sup0 = 0, sup1 = 0, keep0 = 0, keep1 = 0;
    for (int idx = 0; idx < nc; ++idx) {
        bool hi = idx >= 64;
        int bit = idx & 63;
        unsigned long long s = hi ? sup1 : sup0;   // wave-uniform
        if ((s >> bit) & 1ull) continue;           // uniform branch
        if (hi) keep1 |= 1ull << bit; else keep0 |= 1ull << bit;
        float bx_ = hi ? __shfl(A1.x, bit) : __shfl(A0.x, bit);
        float by_ = hi ? __shfl(A1.y, bit) : __shfl(A0.y, bit);
        float bz_ = hi ? __shfl(A1.z, bit) : __shfl(A0.z, bit);
        float bw_ = hi ? __shfl(A1.w, bit) : __shfl(A0.w, bit);
        float ba_ = hi ? __shfl(ar1, bit) : __shfl(ar0, bit);
        bool s0, s1;
        {
            float lx = fmaxf(bx_, A0.x), ly = fmaxf(by_, A0.y);
            float rx = fminf(bz_, A0.z), ry = fminf(bw_, A0.w);
            float iw = fmaxf(rx - lx, 0.0f), ih = fmaxf(ry - ly, 0.0f);
            float inter = iw * ih;
            float iou = inter / (ba_ + ar0 - inter + 1e-7f);  // a_i + a_j order = ref
            s0 = (lane > idx) && (lane < nc) && (iou > 0.45f);
        }
        {
            float lx = fmaxf(bx_, A1.x), ly = fmaxf(by_, A1.y);
            float rx = fminf(bz_, A1.z), ry = fminf(bw_, A1.w);
            float iw = fmaxf(rx - lx, 0.0f), ih = fmaxf(ry - ly, 0.0f);
            float inter = iw * ih;
            float iou = inter / (ba_ + ar1 - inter + 1e-7f);
            s1 = ((64 + lane) > idx) && ((64 + lane) < nc) && (iou > 0.45f);
        }
        sup0 |= __ballot(s0);
        sup1 |= __ballot(s1);
    }
    if (lane < nc && ((keep0 >> lane) & 1ull)) keepG[b * KN + ord0] = 1;
    if (lane + 64 < nc && ((keep1 >> lane) & 1ull)) keepG[b * KN + ord1] = 1;
}

// ---------------------------------------------------------------- output
__global__ __launch_bounds__(64) void out_kernel(const unsigned char* __restrict__ keepG,
        const unsigned long long* __restrict__ gkeys, const float4* __restrict__ gboxes,
        const unsigned char* __restrict__ carrU8, float* __restrict__ out) {
    int b = blockIdx.x;
    int lane = threadIdx.x;
    int running = 0;
    for (int ch = 0; ch < 32; ++ch) {
        int r = ch * 64 + lane;
        bool kp = keepG[b * KN + r] != 0;
        unsigned long long m = __ballot(kp);
        int pos = running + (int)__popcll(m & ((1ull << lane) - 1ull));
        if (kp && pos < MAXD) {
            float4 bx = gboxes[b * KN + r];
            float sc = __uint_as_float((unsigned int)(gkeys[(size_t)b * CAP + r] >> 32));
            float* o = out + ((size_t)b * MAXD + pos) * 6;
            o[0] = bx.x * 3.0f;      // 1920/640
            o[1] = bx.y * 1.6875f;   // 1080/640
            o[2] = bx.z * 3.0f;
            o[3] = bx.w * 1.6875f;
            o[4] = sc;
            o[5] = (float)carrU8[b * KN + r];
        }
        running += (int)__popcll(m);
    }
}

// ---------------------------------------------------------------- launch
extern "C" void kernel_launch(void* const* d_in, const int* in_sizes, int n_in,
                              void* d_out, int out_size, void* d_ws, size_t ws_size,
                              hipStream_t stream) {
    const float* preds = (const float*)d_in[0];
    float* out = (float*)d_out;
    char* ws = (char*)d_ws;
    size_t off = 0;
    auto alloc = [&](size_t bytes) -> void* {
        void* p = ws + off;
        off += (bytes + 255) & ~(size_t)255;
        return p;
    };
    float* score = (float*)alloc((size_t)BS * NP * 4);
    int* cls    = (int*)alloc((size_t)BS * NP * 4);
    int* hpart  = (int*)alloc((size_t)BS * SCB * BINS * 4);   // 4.2 MB
    unsigned long long* gkeys = (unsigned long long*)alloc((size_t)BS * CAP * 8);
    float4* gboxes = (float4*)alloc((size_t)BS * KN * 16);
    unsigned char* carrU8 = (unsigned char*)alloc((size_t)BS * KN);
    unsigned char* keepG  = (unsigned char*)alloc((size_t)BS * KN);
    int* gmeta   = (int*)alloc(BS * 2 * 4);
    int* gbstart = (int*)alloc((size_t)BS * BINS * 4);
    int* gcnt    = (int*)alloc((size_t)BS * BINS * 4);
    if (ws_size < off) return;

    hipMemsetAsync(d_out, 0, (size_t)out_size * 4, stream);

    score_hist_kernel<<<BS * SCB, 256, 0, stream>>>(preds, score, cls, hpart);
    thresh_kernel<<<BS, 512, 0, stream>>>(hpart, gmeta, gbstart, gcnt, carrU8, keepG);
    scatter_kernel<<<BS * SCB, 256, 0, stream>>>(score, hpart, gmeta, gkeys);
    binsort_build_kernel<<<BS * 32, 256, 0, stream>>>(preds, cls, gkeys, gmeta,
                                                      gbstart, gcnt, gboxes, carrU8);
    nms_kernel<<<BS * NC, 64, 0, stream>>>(gboxes, carrU8, gmeta, keepG);
    out_kernel<<<BS, 64, 0, stream>>>(keepG, gkeys, gboxes, carrU8, out);
}